// Round 9
// baseline (119.989 us; speedup 1.0000x reference)
//
#include <hip/hip_runtime.h>

// YOLO loss: N=8192, S=14, B=2, C=20. ncells = N*S*S = 1,605,632.
// d_in[0] pred (ncells*30 f32), d_in[1] tbox (ncells*4 f32),
// d_in[2] tcls (ncells*20 f32), d_in[3] mask (ncells, dtype detected per block)
// d_out: 5 f32 = [total, reg, contain, noobj, cls] / N
//
// R9: SINGLE kernel. Last-block-done grand reduce (counter memset each launch).
// CPT=4; all masks then all 8 conf dwords issued before any use (deep MLP).
// Inactive cells: only the 2 conf dwords. Active (~15%): R6/R8 proven windows.

#define L_COORD 5.0f
#define L_NOOBJ 0.5f
#define BLK 256
#define CPT 4
#define CHUNK (BLK * CPT)   // 1024 cells/block -> 1568 blocks

// ws layout: float4 partials[nblocks] at byte 0; unsigned counter at byte 32768.

__launch_bounds__(256)
__global__ void yolo_loss_kernel(const float* __restrict__ pred,
                                 const float* __restrict__ tbox,
                                 const float* __restrict__ tcls,
                                 const void* __restrict__ mask,
                                 float4* __restrict__ partials,
                                 unsigned int* __restrict__ counter,
                                 float* __restrict__ out,
                                 int ncells, int nblocks, float inv_n) {
    __shared__ float red[4][4];
    __shared__ int s_vote;
    __shared__ unsigned s_old;

    const float invS = 1.0f / 14.0f;
    const unsigned tid = threadIdx.x;
    const unsigned base = blockIdx.x * CHUNK;
    const unsigned int* mw = (const unsigned int*)mask;

    // ---- per-block mask dtype classification (word {0,1}/{0,1.0f} vs byte) ----
    if (tid == 0) s_vote = 0;
    __syncthreads();
    {
        int maxw = (ncells >> 2) - 64;
        int ws = (int)(base >> 2);
        if (ws > maxw) ws = maxw;
        if (ws < 0) ws = 0;
        unsigned v = mw[ws + (tid & 63)];
        bool byteEvid = ((v & 0x01010100u) != 0u) && ((v & ~0x01010101u) == 0u);
        if (byteEvid) atomicOr(&s_vote, 1);
    }
    __syncthreads();
    const bool isByte = (s_vote & 1);

    float a_reg = 0.f, a_con = 0.f, a_noo = 0.f, a_cls = 0.f;

    // ---- phase 1: masks for CPT cells (coalesced) ----
    float fm[CPT];
    bool valid[CPT];
    #pragma unroll
    for (int k = 0; k < CPT; ++k) {
        unsigned c = base + tid + k * BLK;
        valid[k] = (c < (unsigned)ncells);
        unsigned cs = valid[k] ? c : 0u;
        if (isByte) fm[k] = (((const unsigned char*)mask)[cs] != 0) ? 1.0f : 0.0f;
        else        fm[k] = (mw[cs] != 0u) ? 1.0f : 0.0f;
    }

    // ---- phase 2: ALL conf dwords issued back-to-back (8 loads in flight) ----
    float cfa[CPT], cfb[CPT];
    #pragma unroll
    for (int k = 0; k < CPT; ++k) {
        unsigned c = base + tid + k * BLK;
        unsigned cs = valid[k] ? c : 0u;
        const float* row = pred + (size_t)cs * 30u;
        cfa[k] = row[4];
        cfb[k] = row[9];
    }

    // ---- phase 3: noobj for inactive cells ----
    #pragma unroll
    for (int k = 0; k < CPT; ++k) {
        if (valid[k] && fm[k] == 0.0f)
            a_noo += cfa[k] * cfa[k] + cfb[k] * cfb[k];
    }

    // ---- phase 4: heavy path for active cells (~15%) ----
    #pragma unroll
    for (int k = 0; k < CPT; ++k) {
        if (!valid[k] || fm[k] == 0.0f) continue;
        unsigned c = base + tid + k * BLK;
        float cf0 = cfa[k], cf1 = cfb[k];

        unsigned off = c * 120u;
        unsigned a = off & ~15u;
        bool sh = (off != a);
        const float4* pa4 = (const float4*)((const char*)pred + a);
        float4 q0 = pa4[0], q1 = pa4[1], q2 = pa4[2];

        float px0 = sh ? q0.z : q0.x;
        float py0 = sh ? q0.w : q0.y;
        float pw0 = sh ? q1.x : q0.z;
        float ph0 = sh ? q1.y : q0.w;
        float px1 = sh ? q1.w : q1.y;
        float py1 = sh ? q2.x : q1.z;
        float pw1 = sh ? q2.y : q1.w;
        float ph1 = sh ? q2.z : q2.x;

        unsigned off2 = off + 40u;
        unsigned a2 = off2 & ~15u;
        bool s2c = (off2 != a2);
        const float4* ca4 = (const float4*)((const char*)pred + a2);
        float W[22];
        {
            float4 u0 = ca4[0], u1 = ca4[1], u2 = ca4[2], u3 = ca4[3], u4 = ca4[4];
            W[0]=u0.x; W[1]=u0.y; W[2]=u0.z; W[3]=u0.w;
            W[4]=u1.x; W[5]=u1.y; W[6]=u1.z; W[7]=u1.w;
            W[8]=u2.x; W[9]=u2.y; W[10]=u2.z; W[11]=u2.w;
            W[12]=u3.x; W[13]=u3.y; W[14]=u3.z; W[15]=u3.w;
            W[16]=u4.x; W[17]=u4.y; W[18]=u4.z; W[19]=u4.w;
            W[20] = 0.f; W[21] = 0.f;
            if (s2c) {
                float2 e = *(const float2*)((const char*)pred + a2 + 80u);
                W[20] = e.x; W[21] = e.y;
            }
        }

        const float4* tc4 = (const float4*)((const char*)tcls + c * 80u);
        float cl = 0.f;
        #pragma unroll
        for (int i = 0; i < 5; ++i) {
            float4 t = tc4[i];
            float p0 = s2c ? W[4*i+2] : W[4*i+0];
            float p1 = s2c ? W[4*i+3] : W[4*i+1];
            float p2 = s2c ? W[4*i+4] : W[4*i+2];
            float p3 = s2c ? W[4*i+5] : W[4*i+3];
            float d0 = p0 - t.x, d1 = p1 - t.y, d2 = p2 - t.z, d3 = p3 - t.w;
            cl += d0 * d0 + d1 * d1 + d2 * d2 + d3 * d3;
        }
        a_cls += cl;

        float4 tb = *(const float4*)((const char*)tbox + c * 16u);
        float tx1 = tb.x * invS - 0.5f * tb.z;
        float ty1 = tb.y * invS - 0.5f * tb.w;
        float tx2 = tb.x * invS + 0.5f * tb.z;
        float ty2 = tb.y * invS + 0.5f * tb.w;
        float ta  = (tx2 - tx1) * (ty2 - ty1);

        float x1 = px0 * invS - 0.5f * pw0, y1 = py0 * invS - 0.5f * ph0;
        float x2 = px0 * invS + 0.5f * pw0, y2 = py0 * invS + 0.5f * ph0;
        float lx = fmaxf(x1, tx1), ly = fmaxf(y1, ty1);
        float rx = fminf(x2, tx2), ry = fminf(y2, ty2);
        float wx = fmaxf(rx - lx, 0.f), wy = fmaxf(ry - ly, 0.f);
        float inter = wx * wy;
        float pa = (x2 - x1) * (y2 - y1);
        float iou0 = inter / (pa + ta - inter);

        x1 = px1 * invS - 0.5f * pw1; y1 = py1 * invS - 0.5f * ph1;
        x2 = px1 * invS + 0.5f * pw1; y2 = py1 * invS + 0.5f * ph1;
        lx = fmaxf(x1, tx1); ly = fmaxf(y1, ty1);
        rx = fminf(x2, tx2); ry = fminf(y2, ty2);
        wx = fmaxf(rx - lx, 0.f); wy = fmaxf(ry - ly, 0.f);
        inter = wx * wy;
        pa = (x2 - x1) * (y2 - y1);
        float iou1 = inter / (pa + ta - inter);

        // jnp.argmax: first index on tie -> box1 wins only if strictly greater
        int best = (iou1 > iou0) ? 1 : 0;
        float miou = fmaxf(iou0, iou1);

        float bx = best ? px1 : px0, by = best ? py1 : py0;
        float bw = best ? pw1 : pw0, bh = best ? ph1 : ph0;
        float bc = best ? cf1 : cf0;

        float dx = bx - tb.x, dy = by - tb.y;
        float sw = sqrtf(fmaxf(bw, 0.f)) - sqrtf(fmaxf(tb.z, 0.f));
        float sh2 = sqrtf(fmaxf(bh, 0.f)) - sqrtf(fmaxf(tb.w, 0.f));
        a_reg += dx * dx + dy * dy + sw * sw + sh2 * sh2;
        float dc = bc - miou;
        a_con += dc * dc;
    }

    // ---- wave reduce, block reduce, partial store ----
    #pragma unroll
    for (int off = 32; off > 0; off >>= 1) {
        a_reg += __shfl_down(a_reg, off, 64);
        a_con += __shfl_down(a_con, off, 64);
        a_noo += __shfl_down(a_noo, off, 64);
        a_cls += __shfl_down(a_cls, off, 64);
    }
    const int wid = threadIdx.x >> 6, lane = threadIdx.x & 63;
    if (lane == 0) {
        red[wid][0] = a_reg; red[wid][1] = a_con;
        red[wid][2] = a_noo; red[wid][3] = a_cls;
    }
    __syncthreads();
    if (tid == 0) {
        float rg = 0.f, co = 0.f, no = 0.f, cl = 0.f;
        #pragma unroll
        for (int w = 0; w < 4; ++w) {
            rg += red[w][0]; co += red[w][1]; no += red[w][2]; cl += red[w][3];
        }
        partials[blockIdx.x] = make_float4(rg, co, no, cl);
        __threadfence();                         // partial visible before count
        s_old = atomicAdd(counter, 1u);          // device-scope
    }
    __syncthreads();

    // ---- last block: grand reduce ----
    if (s_old == (unsigned)(nblocks - 1)) {
        __threadfence();                         // acquire all partials
        float rg = 0.f, co = 0.f, no = 0.f, cl = 0.f;
        for (int i = (int)tid; i < nblocks; i += BLK) {
            float4 p = partials[i];
            rg += p.x; co += p.y; no += p.z; cl += p.w;
        }
        #pragma unroll
        for (int off = 32; off > 0; off >>= 1) {
            rg += __shfl_down(rg, off, 64);
            co += __shfl_down(co, off, 64);
            no += __shfl_down(no, off, 64);
            cl += __shfl_down(cl, off, 64);
        }
        __syncthreads();                         // red[][] reuse
        if (lane == 0) { red[wid][0] = rg; red[wid][1] = co; red[wid][2] = no; red[wid][3] = cl; }
        __syncthreads();
        if (tid == 0) {
            float r = 0.f, c2 = 0.f, n2 = 0.f, c3 = 0.f;
            #pragma unroll
            for (int w = 0; w < 4; ++w) { r += red[w][0]; c2 += red[w][1]; n2 += red[w][2]; c3 += red[w][3]; }
            float total = c3 + L_NOOBJ * n2 + L_COORD * r + c2;
            out[0] = total * inv_n;
            out[1] = r  * inv_n;
            out[2] = c2 * inv_n;
            out[3] = n2 * inv_n;
            out[4] = c3 * inv_n;
        }
    }
}

extern "C" void kernel_launch(void* const* d_in, const int* in_sizes, int n_in,
                              void* d_out, int out_size, void* d_ws, size_t ws_size,
                              hipStream_t stream) {
    const float* pred = (const float*)d_in[0];
    const float* tbox = (const float*)d_in[1];
    const float* tcls = (const float*)d_in[2];
    const void*  mask = d_in[3];
    const int ncells = in_sizes[3];            // N*S*S = 1,605,632
    const int N = ncells / (14 * 14);
    const int nblocks = (ncells + CHUNK - 1) / CHUNK;   // 1568

    float4*       partials = (float4*)d_ws;
    unsigned int* counter  = (unsigned int*)((char*)d_ws + 32768);

    // zero the arrival counter each launch (memset node is graph-capturable)
    hipMemsetAsync(counter, 0, sizeof(unsigned int), stream);

    yolo_loss_kernel<<<nblocks, BLK, 0, stream>>>(pred, tbox, tcls, mask,
                                                  partials, counter, (float*)d_out,
                                                  ncells, nblocks, 1.0f / (float)N);
}

// Round 10
// 57.374 us; speedup vs baseline: 2.0913x; 2.0913x over previous
//
#include <hip/hip_runtime.h>

// YOLO loss: N=8192, S=14, B=2, C=20. ncells = N*S*S = 1,605,632.
// d_in[0] pred (ncells*30 f32), d_in[1] tbox (ncells*4 f32),
// d_in[2] tcls (ncells*20 f32), d_in[3] mask (ncells, dtype detected per block)
// d_out: 5 f32 = [total, reg, contain, noobj, cls] / N
//
// R10: R8's proven two-kernel structure (51.3us) + R9's deep conf pipeline:
// CPT=4; all masks coalesced, then all 8 conf dwords back-to-back, then noobj,
// then heavy path (15%). NO threadfence/counter epilogue (R9's 3.4x regression:
// per-block device-scope fence+atomic ~80ns each on 8-XCD CDNA4).

#define L_COORD 5.0f
#define L_NOOBJ 0.5f
#define BLK 256
#define CPT 4
#define CHUNK (BLK * CPT)   // 1024 cells/block -> 1568 blocks

__launch_bounds__(256)
__global__ void yolo_loss_kernel(const float* __restrict__ pred,
                                 const float* __restrict__ tbox,
                                 const float* __restrict__ tcls,
                                 const void* __restrict__ mask,
                                 float4* __restrict__ partials,
                                 int ncells) {
    __shared__ float red[4][4];
    __shared__ int s_vote;

    const float invS = 1.0f / 14.0f;
    const unsigned tid = threadIdx.x;
    const unsigned base = blockIdx.x * CHUNK;
    const unsigned int* mw = (const unsigned int*)mask;

    // ---- per-block mask dtype classification (word {0,1}/{0,1.0f} vs byte) ----
    if (tid == 0) s_vote = 0;
    __syncthreads();
    {
        int maxw = (ncells >> 2) - 64;
        int ws = (int)(base >> 2);
        if (ws > maxw) ws = maxw;
        if (ws < 0) ws = 0;
        unsigned v = mw[ws + (tid & 63)];
        bool byteEvid = ((v & 0x01010100u) != 0u) && ((v & ~0x01010101u) == 0u);
        if (byteEvid) atomicOr(&s_vote, 1);
    }
    __syncthreads();
    const bool isByte = (s_vote & 1);

    float a_reg = 0.f, a_con = 0.f, a_noo = 0.f, a_cls = 0.f;

    // ---- phase 1: masks for CPT cells (coalesced) ----
    float fm[CPT];
    bool valid[CPT];
    #pragma unroll
    for (int k = 0; k < CPT; ++k) {
        unsigned c = base + tid + k * BLK;
        valid[k] = (c < (unsigned)ncells);
        unsigned cs = valid[k] ? c : 0u;
        if (isByte) fm[k] = (((const unsigned char*)mask)[cs] != 0) ? 1.0f : 0.0f;
        else        fm[k] = (mw[cs] != 0u) ? 1.0f : 0.0f;
    }

    // ---- phase 2: ALL conf dwords issued back-to-back (8 loads in flight) ----
    float cfa[CPT], cfb[CPT];
    #pragma unroll
    for (int k = 0; k < CPT; ++k) {
        unsigned c = base + tid + k * BLK;
        unsigned cs = valid[k] ? c : 0u;
        const float* row = pred + (size_t)cs * 30u;
        cfa[k] = row[4];
        cfb[k] = row[9];
    }

    // ---- phase 3: noobj for inactive cells ----
    #pragma unroll
    for (int k = 0; k < CPT; ++k) {
        if (valid[k] && fm[k] == 0.0f)
            a_noo += cfa[k] * cfa[k] + cfb[k] * cfb[k];
    }

    // ---- phase 4: heavy path for active cells (~15%) ----
    #pragma unroll
    for (int k = 0; k < CPT; ++k) {
        if (!valid[k] || fm[k] == 0.0f) continue;
        unsigned c = base + tid + k * BLK;
        float cf0 = cfa[k], cf1 = cfb[k];

        unsigned off = c * 120u;
        unsigned a = off & ~15u;
        bool sh = (off != a);
        const float4* pa4 = (const float4*)((const char*)pred + a);
        float4 q0 = pa4[0], q1 = pa4[1], q2 = pa4[2];

        float px0 = sh ? q0.z : q0.x;
        float py0 = sh ? q0.w : q0.y;
        float pw0 = sh ? q1.x : q0.z;
        float ph0 = sh ? q1.y : q0.w;
        float px1 = sh ? q1.w : q1.y;
        float py1 = sh ? q2.x : q1.z;
        float pw1 = sh ? q2.y : q1.w;
        float ph1 = sh ? q2.z : q2.x;

        unsigned off2 = off + 40u;
        unsigned a2 = off2 & ~15u;
        bool s2c = (off2 != a2);
        const float4* ca4 = (const float4*)((const char*)pred + a2);
        float W[22];
        {
            float4 u0 = ca4[0], u1 = ca4[1], u2 = ca4[2], u3 = ca4[3], u4 = ca4[4];
            W[0]=u0.x; W[1]=u0.y; W[2]=u0.z; W[3]=u0.w;
            W[4]=u1.x; W[5]=u1.y; W[6]=u1.z; W[7]=u1.w;
            W[8]=u2.x; W[9]=u2.y; W[10]=u2.z; W[11]=u2.w;
            W[12]=u3.x; W[13]=u3.y; W[14]=u3.z; W[15]=u3.w;
            W[16]=u4.x; W[17]=u4.y; W[18]=u4.z; W[19]=u4.w;
            W[20] = 0.f; W[21] = 0.f;
            if (s2c) {
                float2 e = *(const float2*)((const char*)pred + a2 + 80u);
                W[20] = e.x; W[21] = e.y;
            }
        }

        const float4* tc4 = (const float4*)((const char*)tcls + c * 80u);
        float cl = 0.f;
        #pragma unroll
        for (int i = 0; i < 5; ++i) {
            float4 t = tc4[i];
            float p0 = s2c ? W[4*i+2] : W[4*i+0];
            float p1 = s2c ? W[4*i+3] : W[4*i+1];
            float p2 = s2c ? W[4*i+4] : W[4*i+2];
            float p3 = s2c ? W[4*i+5] : W[4*i+3];
            float d0 = p0 - t.x, d1 = p1 - t.y, d2 = p2 - t.z, d3 = p3 - t.w;
            cl += d0 * d0 + d1 * d1 + d2 * d2 + d3 * d3;
        }
        a_cls += cl;

        float4 tb = *(const float4*)((const char*)tbox + c * 16u);
        float tx1 = tb.x * invS - 0.5f * tb.z;
        float ty1 = tb.y * invS - 0.5f * tb.w;
        float tx2 = tb.x * invS + 0.5f * tb.z;
        float ty2 = tb.y * invS + 0.5f * tb.w;
        float ta  = (tx2 - tx1) * (ty2 - ty1);

        float x1 = px0 * invS - 0.5f * pw0, y1 = py0 * invS - 0.5f * ph0;
        float x2 = px0 * invS + 0.5f * pw0, y2 = py0 * invS + 0.5f * ph0;
        float lx = fmaxf(x1, tx1), ly = fmaxf(y1, ty1);
        float rx = fminf(x2, tx2), ry = fminf(y2, ty2);
        float wx = fmaxf(rx - lx, 0.f), wy = fmaxf(ry - ly, 0.f);
        float inter = wx * wy;
        float pa = (x2 - x1) * (y2 - y1);
        float iou0 = inter / (pa + ta - inter);

        x1 = px1 * invS - 0.5f * pw1; y1 = py1 * invS - 0.5f * ph1;
        x2 = px1 * invS + 0.5f * pw1; y2 = py1 * invS + 0.5f * ph1;
        lx = fmaxf(x1, tx1); ly = fmaxf(y1, ty1);
        rx = fminf(x2, tx2); ry = fminf(y2, ty2);
        wx = fmaxf(rx - lx, 0.f); wy = fmaxf(ry - ly, 0.f);
        inter = wx * wy;
        pa = (x2 - x1) * (y2 - y1);
        float iou1 = inter / (pa + ta - inter);

        // jnp.argmax: first index on tie -> box1 wins only if strictly greater
        int best = (iou1 > iou0) ? 1 : 0;
        float miou = fmaxf(iou0, iou1);

        float bx = best ? px1 : px0, by = best ? py1 : py0;
        float bw = best ? pw1 : pw0, bh = best ? ph1 : ph0;
        float bc = best ? cf1 : cf0;

        float dx = bx - tb.x, dy = by - tb.y;
        float sw = sqrtf(fmaxf(bw, 0.f)) - sqrtf(fmaxf(tb.z, 0.f));
        float sh2 = sqrtf(fmaxf(bh, 0.f)) - sqrtf(fmaxf(tb.w, 0.f));
        a_reg += dx * dx + dy * dy + sw * sw + sh2 * sh2;
        float dc = bc - miou;
        a_con += dc * dc;
    }

    // ---- wave reduce, block reduce, ONE uncontended partial store ----
    #pragma unroll
    for (int off = 32; off > 0; off >>= 1) {
        a_reg += __shfl_down(a_reg, off, 64);
        a_con += __shfl_down(a_con, off, 64);
        a_noo += __shfl_down(a_noo, off, 64);
        a_cls += __shfl_down(a_cls, off, 64);
    }
    const int wid = threadIdx.x >> 6, lane = threadIdx.x & 63;
    if (lane == 0) {
        red[wid][0] = a_reg; red[wid][1] = a_con;
        red[wid][2] = a_noo; red[wid][3] = a_cls;
    }
    __syncthreads();
    if (tid == 0) {
        float rg = 0.f, co = 0.f, no = 0.f, cl = 0.f;
        #pragma unroll
        for (int w = 0; w < 4; ++w) {
            rg += red[w][0]; co += red[w][1]; no += red[w][2]; cl += red[w][3];
        }
        partials[blockIdx.x] = make_float4(rg, co, no, cl);
    }
}

__launch_bounds__(256)
__global__ void reduce_kernel(const float4* __restrict__ partials, int nblocks,
                              float* __restrict__ out, float inv_n) {
    __shared__ float red[4][4];
    float rg = 0.f, co = 0.f, no = 0.f, cl = 0.f;
    for (int i = threadIdx.x; i < nblocks; i += blockDim.x) {
        float4 p = partials[i];
        rg += p.x; co += p.y; no += p.z; cl += p.w;
    }
    #pragma unroll
    for (int off = 32; off > 0; off >>= 1) {
        rg += __shfl_down(rg, off, 64);
        co += __shfl_down(co, off, 64);
        no += __shfl_down(no, off, 64);
        cl += __shfl_down(cl, off, 64);
    }
    const int wid = threadIdx.x >> 6, lane = threadIdx.x & 63;
    if (lane == 0) { red[wid][0] = rg; red[wid][1] = co; red[wid][2] = no; red[wid][3] = cl; }
    __syncthreads();
    if (threadIdx.x == 0) {
        float r = 0.f, c2 = 0.f, n2 = 0.f, c3 = 0.f;
        #pragma unroll
        for (int w = 0; w < 4; ++w) { r += red[w][0]; c2 += red[w][1]; n2 += red[w][2]; c3 += red[w][3]; }
        float total = c3 + L_NOOBJ * n2 + L_COORD * r + c2;
        out[0] = total * inv_n;
        out[1] = r  * inv_n;
        out[2] = c2 * inv_n;
        out[3] = n2 * inv_n;
        out[4] = c3 * inv_n;
    }
}

extern "C" void kernel_launch(void* const* d_in, const int* in_sizes, int n_in,
                              void* d_out, int out_size, void* d_ws, size_t ws_size,
                              hipStream_t stream) {
    const float* pred = (const float*)d_in[0];
    const float* tbox = (const float*)d_in[1];
    const float* tcls = (const float*)d_in[2];
    const void*  mask = d_in[3];
    const int ncells = in_sizes[3];            // N*S*S = 1,605,632
    const int N = ncells / (14 * 14);
    const int nblocks = (ncells + CHUNK - 1) / CHUNK;   // 1568

    float4* partials = (float4*)d_ws;

    yolo_loss_kernel<<<nblocks, BLK, 0, stream>>>(pred, tbox, tcls, mask,
                                                  partials, ncells);

    reduce_kernel<<<1, 256, 0, stream>>>(partials, nblocks, (float*)d_out, 1.0f / (float)N);
}

// Round 11
// 51.436 us; speedup vs baseline: 2.3328x; 1.1155x over previous
//
#include <hip/hip_runtime.h>

// YOLO loss: N=8192, S=14, B=2, C=20. ncells = N*S*S = 1,605,632.
// d_in[0] pred (ncells*30 f32), d_in[1] tbox (ncells*4 f32),
// d_in[2] tcls (ncells*20 f32), d_in[3] mask (ncells, dtype detected per block)
// d_out: 5 f32 = [total, reg, contain, noobj, cls] / N
//
// R11 == R8 exactly (best measured: 51.3us). Two kernels, CPT=2.
// Inactive cells (85%): ONLY 2 conf dwords. Active (15%): aligned-window path.
// Converged wall: ~250MB line-granular traffic at ~5.4 TB/s cache-fabric rate;
// traffic is irreducible (every 128B pred line overlaps a conf window).

#define L_COORD 5.0f
#define L_NOOBJ 0.5f
#define BLK 256
#define CPT 2
#define CHUNK (BLK * CPT)   // 512 cells per block -> 3136 blocks

__launch_bounds__(256)
__global__ void yolo_loss_kernel(const float* __restrict__ pred,
                                 const float* __restrict__ tbox,
                                 const float* __restrict__ tcls,
                                 const void* __restrict__ mask,
                                 float4* __restrict__ partials,
                                 int ncells) {
    __shared__ float red[4][4];
    __shared__ int s_vote;

    const float invS = 1.0f / 14.0f;
    const unsigned tid = threadIdx.x;
    const unsigned base = blockIdx.x * CHUNK;
    const unsigned int* mw = (const unsigned int*)mask;

    // ---- per-block mask dtype classification (word {0,1}/{0,1.0f} vs byte) ----
    if (tid == 0) s_vote = 0;
    __syncthreads();
    {
        int maxw = (ncells >> 2) - 64;
        int ws = (int)(base >> 2);
        if (ws > maxw) ws = maxw;
        if (ws < 0) ws = 0;
        unsigned v = mw[ws + (tid & 63)];
        bool byteEvid = ((v & 0x01010100u) != 0u) && ((v & ~0x01010101u) == 0u);
        if (byteEvid) atomicOr(&s_vote, 1);
    }
    __syncthreads();
    const bool isByte = (s_vote & 1);

    float a_reg = 0.f, a_con = 0.f, a_noo = 0.f, a_cls = 0.f;

    // ---- phase 1: masks for CPT cells (coalesced) ----
    float fm[CPT];
    bool valid[CPT];
    #pragma unroll
    for (int k = 0; k < CPT; ++k) {
        unsigned c = base + tid + k * BLK;
        valid[k] = (c < (unsigned)ncells);
        unsigned cs = valid[k] ? c : 0u;
        if (isByte) fm[k] = (((const unsigned char*)mask)[cs] != 0) ? 1.0f : 0.0f;
        else        fm[k] = (mw[cs] != 0u) ? 1.0f : 0.0f;
    }

    // ---- phase 2: per-cell work; inactive = 2 dwords only ----
    #pragma unroll
    for (int k = 0; k < CPT; ++k) {
        if (!valid[k]) continue;
        unsigned c = base + tid + k * BLK;
        const float* row = pred + (size_t)c * 30u;

        if (fm[k] == 0.0f) {
            // noobj only: conf words 4 and 9
            float cf0 = row[4], cf1 = row[9];
            a_noo += cf0 * cf0 + cf1 * cf1;
        } else {
            // ---- full active path (aligned windows, all within the row) ----
            unsigned off = c * 120u;
            unsigned a = off & ~15u;
            bool sh = (off != a);
            const float4* pa4 = (const float4*)((const char*)pred + a);
            float4 q0 = pa4[0], q1 = pa4[1], q2 = pa4[2];

            float px0 = sh ? q0.z : q0.x;
            float py0 = sh ? q0.w : q0.y;
            float pw0 = sh ? q1.x : q0.z;
            float ph0 = sh ? q1.y : q0.w;
            float cf0 = sh ? q1.z : q1.x;
            float px1 = sh ? q1.w : q1.y;
            float py1 = sh ? q2.x : q1.z;
            float pw1 = sh ? q2.y : q1.w;
            float ph1 = sh ? q2.z : q2.x;
            float cf1 = sh ? q2.w : q2.y;

            unsigned off2 = off + 40u;
            unsigned a2 = off2 & ~15u;
            bool s2c = (off2 != a2);
            const float4* ca4 = (const float4*)((const char*)pred + a2);
            float W[22];
            {
                float4 u0 = ca4[0], u1 = ca4[1], u2 = ca4[2], u3 = ca4[3], u4 = ca4[4];
                W[0]=u0.x; W[1]=u0.y; W[2]=u0.z; W[3]=u0.w;
                W[4]=u1.x; W[5]=u1.y; W[6]=u1.z; W[7]=u1.w;
                W[8]=u2.x; W[9]=u2.y; W[10]=u2.z; W[11]=u2.w;
                W[12]=u3.x; W[13]=u3.y; W[14]=u3.z; W[15]=u3.w;
                W[16]=u4.x; W[17]=u4.y; W[18]=u4.z; W[19]=u4.w;
                W[20] = 0.f; W[21] = 0.f;
                if (s2c) {
                    float2 e = *(const float2*)((const char*)pred + a2 + 80u);
                    W[20] = e.x; W[21] = e.y;
                }
            }

            const float4* tc4 = (const float4*)((const char*)tcls + c * 80u);
            float cl = 0.f;
            #pragma unroll
            for (int i = 0; i < 5; ++i) {
                float4 t = tc4[i];
                float p0 = s2c ? W[4*i+2] : W[4*i+0];
                float p1 = s2c ? W[4*i+3] : W[4*i+1];
                float p2 = s2c ? W[4*i+4] : W[4*i+2];
                float p3 = s2c ? W[4*i+5] : W[4*i+3];
                float d0 = p0 - t.x, d1 = p1 - t.y, d2 = p2 - t.z, d3 = p3 - t.w;
                cl += d0 * d0 + d1 * d1 + d2 * d2 + d3 * d3;
            }
            a_cls += cl;

            float4 tb = *(const float4*)((const char*)tbox + c * 16u);
            float tx1 = tb.x * invS - 0.5f * tb.z;
            float ty1 = tb.y * invS - 0.5f * tb.w;
            float tx2 = tb.x * invS + 0.5f * tb.z;
            float ty2 = tb.y * invS + 0.5f * tb.w;
            float ta  = (tx2 - tx1) * (ty2 - ty1);

            float x1 = px0 * invS - 0.5f * pw0, y1 = py0 * invS - 0.5f * ph0;
            float x2 = px0 * invS + 0.5f * pw0, y2 = py0 * invS + 0.5f * ph0;
            float lx = fmaxf(x1, tx1), ly = fmaxf(y1, ty1);
            float rx = fminf(x2, tx2), ry = fminf(y2, ty2);
            float wx = fmaxf(rx - lx, 0.f), wy = fmaxf(ry - ly, 0.f);
            float inter = wx * wy;
            float pa = (x2 - x1) * (y2 - y1);
            float iou0 = inter / (pa + ta - inter);

            x1 = px1 * invS - 0.5f * pw1; y1 = py1 * invS - 0.5f * ph1;
            x2 = px1 * invS + 0.5f * pw1; y2 = py1 * invS + 0.5f * ph1;
            lx = fmaxf(x1, tx1); ly = fmaxf(y1, ty1);
            rx = fminf(x2, tx2); ry = fminf(y2, ty2);
            wx = fmaxf(rx - lx, 0.f); wy = fmaxf(ry - ly, 0.f);
            inter = wx * wy;
            pa = (x2 - x1) * (y2 - y1);
            float iou1 = inter / (pa + ta - inter);

            // jnp.argmax: first index on tie -> box1 wins only if strictly greater
            int best = (iou1 > iou0) ? 1 : 0;
            float miou = fmaxf(iou0, iou1);

            float bx = best ? px1 : px0, by = best ? py1 : py0;
            float bw = best ? pw1 : pw0, bh = best ? ph1 : ph0;
            float bc = best ? cf1 : cf0;

            float dx = bx - tb.x, dy = by - tb.y;
            float sw = sqrtf(fmaxf(bw, 0.f)) - sqrtf(fmaxf(tb.z, 0.f));
            float sh2 = sqrtf(fmaxf(bh, 0.f)) - sqrtf(fmaxf(tb.w, 0.f));
            a_reg += dx * dx + dy * dy + sw * sw + sh2 * sh2;
            float dc = bc - miou;
            a_con += dc * dc;
        }
    }

    // ---- wave reduce, block reduce, ONE uncontended partial store ----
    #pragma unroll
    for (int off = 32; off > 0; off >>= 1) {
        a_reg += __shfl_down(a_reg, off, 64);
        a_con += __shfl_down(a_con, off, 64);
        a_noo += __shfl_down(a_noo, off, 64);
        a_cls += __shfl_down(a_cls, off, 64);
    }
    const int wid = threadIdx.x >> 6, lane = threadIdx.x & 63;
    if (lane == 0) {
        red[wid][0] = a_reg; red[wid][1] = a_con;
        red[wid][2] = a_noo; red[wid][3] = a_cls;
    }
    __syncthreads();
    if (threadIdx.x == 0) {
        float rg = 0.f, co = 0.f, no = 0.f, cl = 0.f;
        #pragma unroll
        for (int w = 0; w < 4; ++w) {
            rg += red[w][0]; co += red[w][1]; no += red[w][2]; cl += red[w][3];
        }
        partials[blockIdx.x] = make_float4(rg, co, no, cl);
    }
}

__launch_bounds__(256)
__global__ void reduce_kernel(const float4* __restrict__ partials, int nblocks,
                              float* __restrict__ out, float inv_n) {
    __shared__ float red[4][4];
    float rg = 0.f, co = 0.f, no = 0.f, cl = 0.f;
    for (int i = threadIdx.x; i < nblocks; i += blockDim.x) {
        float4 p = partials[i];
        rg += p.x; co += p.y; no += p.z; cl += p.w;
    }
    #pragma unroll
    for (int off = 32; off > 0; off >>= 1) {
        rg += __shfl_down(rg, off, 64);
        co += __shfl_down(co, off, 64);
        no += __shfl_down(no, off, 64);
        cl += __shfl_down(cl, off, 64);
    }
    const int wid = threadIdx.x >> 6, lane = threadIdx.x & 63;
    if (lane == 0) { red[wid][0] = rg; red[wid][1] = co; red[wid][2] = no; red[wid][3] = cl; }
    __syncthreads();
    if (threadIdx.x == 0) {
        float r = 0.f, c2 = 0.f, n2 = 0.f, c3 = 0.f;
        #pragma unroll
        for (int w = 0; w < 4; ++w) { r += red[w][0]; c2 += red[w][1]; n2 += red[w][2]; c3 += red[w][3]; }
        float total = c3 + L_NOOBJ * n2 + L_COORD * r + c2;
        out[0] = total * inv_n;
        out[1] = r  * inv_n;
        out[2] = c2 * inv_n;
        out[3] = n2 * inv_n;
        out[4] = c3 * inv_n;
    }
}

extern "C" void kernel_launch(void* const* d_in, const int* in_sizes, int n_in,
                              void* d_out, int out_size, void* d_ws, size_t ws_size,
                              hipStream_t stream) {
    const float* pred = (const float*)d_in[0];
    const float* tbox = (const float*)d_in[1];
    const float* tcls = (const float*)d_in[2];
    const void*  mask = d_in[3];
    const int ncells = in_sizes[3];            // N*S*S = 1,605,632
    const int N = ncells / (14 * 14);
    const int nblocks = (ncells + CHUNK - 1) / CHUNK;   // 3136

    float4* partials = (float4*)d_ws;

    yolo_loss_kernel<<<nblocks, BLK, 0, stream>>>(pred, tbox, tcls, mask,
                                                  partials, ncells);

    reduce_kernel<<<1, 256, 0, stream>>>(partials, nblocks, (float*)d_out, 1.0f / (float)N);
}